// Round 2
// 4782.693 us; speedup vs baseline: 1.2215x; 1.2215x over previous
//
#include <hip/hip_runtime.h>
#include <stdint.h>

// TrianDecoder: 4-layer LSTM (B=32, T=64, H=1024) + vocab projection (V=32000) + softmax.
// This revision: REGISTER-RESIDENT LSTM WEIGHTS (re-submit; previous bench was an
// infra failure with no counters).
// The grid barrier's agent-scope acquire invalidates L1/L2 every step, so weights can
// never be cached across steps -> the round-0 version re-fetched 2.4 GB of weights (the
// whole 4.7 ms). Now: 256 KB of weights per CU live in VGPRs (128 VGPRs/wave, 8 waves,
// loaded once) and survive all 256 barrier steps. Cell state c lives in gate-thread
// registers (fp32), removing the cbuf global round-trip too.

#define NL 4
#define BB 32
#define TT 64
#define HH 1024
#define VV 32000

typedef __attribute__((ext_vector_type(8))) short bf16x8;
typedef __attribute__((ext_vector_type(4))) float f32x4;

__device__ __forceinline__ unsigned short f2bf(float f) {
  union { float f; unsigned u; } v; v.f = f;
  unsigned u = v.u;
  u = u + 0x7fffu + ((u >> 16) & 1u);   // RNE
  return (unsigned short)(u >> 16);
}

// ---------------------------------------------------------------------------
// Generic weight swizzler: src fp32 row-major (K x N), dst bf16 fragment layout
// [nt][kq][lane][8] for mfma_f32_16x16x32_bf16 A/B operands:
//   lane holds elem [row/col = tilebase + (lane&15)][k = kq*32 + (lane>>4)*8 + j]
// mode 0 (plain):  col(nt,i) = nt*16 + i                     (Wfc)
// mode 1 (lstm):   col(nt,i) = (i>>2)*1024 + nt*4 + (i&3)    (gate-interleaved tiles)
// ---------------------------------------------------------------------------
__global__ void __launch_bounds__(256)
swizzle_w(const float* __restrict__ src, unsigned short* __restrict__ dst,
          int K, int N, int mode, long long src_lstride, long long dst_lstride) {
  int l = blockIdx.z;
  src += (long long)l * src_lstride;
  dst += (long long)l * dst_lstride;
  int k0  = blockIdx.x * 64;
  int ntb = blockIdx.y;            // group of 4 n-tiles (64 cols)
  __shared__ float lds[64][65];
  int tid = threadIdx.x;
  for (int it = 0; it < 16; ++it) {
    int idx = tid + it * 256;      // 0..4095
    int kk = idx >> 6;
    int cl = idx & 63;
    int col;
    if (mode == 1) col = ((cl >> 4) << 10) + ntb * 16 + (cl & 15);
    else           col = ntb * 64 + cl;
    lds[kk][cl] = src[(long long)(k0 + kk) * N + col];
  }
  __syncthreads();
  int kqn = K >> 5;
  for (int p = 0; p < 2; ++p) {
    int o = tid + p * 256;         // 0..511
    int lane = o & 63;
    int kql  = (o >> 6) & 1;
    int ntl  = o >> 7;             // 0..3
    int i = lane & 15;
    int kloc = kql * 32 + ((lane >> 4) << 3);
    int clocal;
    if (mode == 1) clocal = ((i >> 2) << 4) + ntl * 4 + (i & 3);
    else           clocal = ntl * 16 + i;
    unsigned short o8[8] __attribute__((aligned(16)));
    #pragma unroll
    for (int j = 0; j < 8; ++j) o8[j] = f2bf(lds[kloc + j][clocal]);
    int nt = ntb * 4 + ntl;
    int kq = (k0 >> 5) + kql;
    long long doff = ((((long long)nt * kqn) + kq) << 9) + (lane << 3);
    *reinterpret_cast<uint4*>(dst + doff) = *reinterpret_cast<const uint4*>(o8);
  }
}

// ---------------------------------------------------------------------------
// Embedding gather -> bf16 swizzled activation x_sw[t] ([rt][kq][lane][8], 32768 elems/t)
// ---------------------------------------------------------------------------
__global__ void __launch_bounds__(256)
embed_swz(const int* __restrict__ tok, const float* __restrict__ emb,
          unsigned short* __restrict__ xsw) {
  int gid = blockIdx.x * 256 + threadIdx.x;   // 64t * 2rt * 32kq * 64lane = 262144
  int lane = gid & 63;
  int kq = (gid >> 6) & 31;
  int rt = (gid >> 11) & 1;
  int t  = gid >> 12;
  int r = rt * 16 + (lane & 15);
  int k = kq * 32 + (((lane >> 4) & 3) << 3);
  int token = tok[r * TT + t];                // batch_target_in[b=r][t]
  const float* s = emb + (long long)token * HH + k;
  unsigned short o8[8] __attribute__((aligned(16)));
  #pragma unroll
  for (int j = 0; j < 8; ++j) o8[j] = f2bf(s[j]);
  long long off = (long long)t * 32768 + (((rt * 32 + kq) * 64 + lane) << 3);
  *reinterpret_cast<uint4*>(xsw + off) = *reinterpret_cast<const uint4*>(o8);
}

// ---------------------------------------------------------------------------
// Init h (bf16 swizzled, parity slot 1) from states (c now lives in lstm registers)
// ---------------------------------------------------------------------------
__global__ void __launch_bounds__(256)
init_h(const float* __restrict__ states, unsigned short* __restrict__ hsw) {
  int gid = blockIdx.x * 256 + threadIdx.x;   // 4l * 2rt * 32kq * 64lane = 16384
  int lane = gid & 63;
  int kq = (gid >> 6) & 31;
  int rt = (gid >> 11) & 1;
  int l  = gid >> 12;
  int r = rt * 16 + (lane & 15);
  int k = kq * 32 + (((lane >> 4) & 3) << 3);
  const float* hs = states + (long long)(2 * l) * (BB * HH) + r * HH + k;
  unsigned short o8[8] __attribute__((aligned(16)));
  #pragma unroll
  for (int j = 0; j < 8; ++j) o8[j] = f2bf(hs[j]);
  long long off = (long long)(l * 2 + 1) * 32768 + (((rt * 32 + kq) * 64 + lane) << 3);
  *reinterpret_cast<uint4*>(hsw + off) = *reinterpret_cast<const uint4*>(o8);
}

// ---------------------------------------------------------------------------
// Persistent LSTM kernel: 256 blocks (1/CU) x 512 threads (8 waves), custom grid barrier.
// Block bid owns h-cols {bid*4 .. bid*4+3} -> 16 z-cols {q*1024 + bid*4 + jj}.
// z^T formulation: D[c][r] = (W^T)(c,k) x inp(r,k).
// Wave w: mat = w>>2 (0: Wx*inp, 1: Wh*hprev), K-quarter = w&3 (kq range of 8).
// Each wave holds ALL 4 layers' weight fragments for its (mat, K-quarter) slice in
// registers: 4l x 8kq x bf16x8 = 128 VGPRs. Loaded once; immune to the per-step
// L2 invalidate that the grid barrier's acquire performs.
// ---------------------------------------------------------------------------
__global__ void __launch_bounds__(512, 2)
lstm_kernel(const unsigned short* __restrict__ Wsw,  // [l*2+mat][256ct][32kq][64][8]
            const float* __restrict__ bias,          // (4, 4096)
            const unsigned short* __restrict__ xsw,  // [64t][32768]
            unsigned short* hsw,                     // [l*2+parity][32768]
            const float* __restrict__ states,        // (8, 32, 1024) for c init
            unsigned short* topsw,                   // [64t][32768]
            unsigned* ctr) {
  const int tid  = threadIdx.x;
  const int wave = tid >> 6;
  const int lane = tid & 63;
  const int bid  = blockIdx.x;            // = ct, 0..255
  const int mat  = wave >> 2;             // 0: Wx*inp, 1: Wh*hprev
  const int kqb  = (wave & 3) << 3;       // kq range [kqb, kqb+8)

  __shared__ float zsh[8][16][33];        // [wave][c-local][r]

  // ---- one-time weight preload into registers (128 VGPRs/wave) ----
  bf16x8 wreg[NL][8];
  #pragma unroll
  for (int l = 0; l < NL; ++l) {
    const unsigned short* wb =
        Wsw + ((((l * 2 + mat) * 256 + bid) * 32 + kqb) << 9) + (lane << 3);
    #pragma unroll
    for (int s = 0; s < 8; ++s)
      wreg[l][s] = *reinterpret_cast<const bf16x8*>(wb + (s << 9));
  }

  // ---- cell state in registers (gate threads tid<128: thread = (r, jj)) ----
  const int r    = tid & 31;
  const int jj   = (tid >> 5) & 3;
  const int jcol = bid * 4 + jj;
  float cReg[NL] = {0.f, 0.f, 0.f, 0.f};
  if (tid < 128) {
    #pragma unroll
    for (int l = 0; l < NL; ++l)
      cReg[l] = states[(long long)(2 * l + 1) * (BB * HH) + r * HH + jcol];
  }

  for (int t = 0; t < TT; ++t) {
    #pragma unroll
    for (int l = 0; l < NL; ++l) {
      const unsigned short* ibase;
      if (mat == 0)
        ibase = (l == 0) ? (xsw + (long long)t * 32768)
                         : (hsw + (long long)((l - 1) * 2 + (t & 1)) * 32768);
      else
        ibase = hsw + (long long)(l * 2 + ((t + 1) & 1)) * 32768;
      ibase += (kqb << 9) + (lane << 3);

      f32x4 acc0 = {0.f, 0.f, 0.f, 0.f};
      f32x4 acc1 = {0.f, 0.f, 0.f, 0.f};
      #pragma unroll
      for (int s = 0; s < 8; ++s) {
        bf16x8 b0 = *reinterpret_cast<const bf16x8*>(ibase + (s << 9));
        bf16x8 b1 = *reinterpret_cast<const bf16x8*>(ibase + 16384 + (s << 9));
        acc0 = __builtin_amdgcn_mfma_f32_16x16x32_bf16(wreg[l][s], b0, acc0, 0, 0, 0);
        acc1 = __builtin_amdgcn_mfma_f32_16x16x32_bf16(wreg[l][s], b1, acc1, 0, 0, 0);
      }
      // park partial z^T in LDS: D row m=(lane>>4)*4+reg (c-local), col n=lane&15 (r)
      {
        int i4 = (lane >> 4) << 2;
        int rl = lane & 15;
        #pragma unroll
        for (int reg = 0; reg < 4; ++reg) {
          zsh[wave][i4 + reg][rl]      = acc0[reg];
          zsh[wave][i4 + reg][16 + rl] = acc1[reg];
        }
      }
      __syncthreads();
      // gates: 128 threads, thread = (r, jj); c stays in registers
      if (tid < 128) {
        float zg[4];
        #pragma unroll
        for (int q = 0; q < 4; ++q) {
          int i = q * 4 + jj;
          float z = 0.f;
          #pragma unroll
          for (int w = 0; w < 8; ++w) z += zsh[w][i][r];
          zg[q] = z + bias[(l << 12) + (q << 10) + jcol];
        }
        float si = 1.f / (1.f + __expf(-zg[0]));
        float sf = 1.f / (1.f + __expf(-zg[1]));
        float so = 1.f / (1.f + __expf(-zg[3]));
        float e2 = __expf(-2.f * fabsf(zg[2]));
        float tg = (1.f - e2) / (1.f + e2);
        tg = zg[2] < 0.f ? -tg : tg;
        float cnew = sf * cReg[l] + si * tg;
        cReg[l] = cnew;
        float e2c = __expf(-2.f * fabsf(cnew));
        float th = (1.f - e2c) / (1.f + e2c);
        th = cnew < 0.f ? -th : th;
        unsigned short hb = f2bf(so * th);
        int rt = r >> 4, kq = jcol >> 5;
        int ln = (r & 15) | (((jcol >> 3) & 3) << 4);
        int hoff = (((rt << 5) | kq) << 9) | (ln << 3) | (jcol & 7);
        hsw[(long long)(l * 2 + (t & 1)) * 32768 + hoff] = hb;
        if (l == 3) topsw[(long long)t * 32768 + hoff] = hb;
      }
      // grid barrier (agent-scope: release flushes L2, acquire invalidates)
      __syncthreads();
      if (tid == 0) {
        __hip_atomic_fetch_add(ctr, 1u, __ATOMIC_RELEASE, __HIP_MEMORY_SCOPE_AGENT);
        unsigned tgt = 256u * (unsigned)(t * NL + l + 1);
        while (__hip_atomic_load(ctr, __ATOMIC_RELAXED, __HIP_MEMORY_SCOPE_AGENT) < tgt)
          __builtin_amdgcn_s_sleep(2);
        (void)__hip_atomic_load(ctr, __ATOMIC_ACQUIRE, __HIP_MEMORY_SCOPE_AGENT);
      }
      __syncthreads();
    }
  }
}

// ---------------------------------------------------------------------------
// Projection: logits(2048 x 32000) = tops(2048x1024) @ Wfc(1024x32000) + bfc
// Block = M128 x N256 (4 waves, wave = 8mt x 4nt). Fragment-direct global loads.
// Writes logits into d_out at out[b][t][v] (m = t*32 + b).
// ---------------------------------------------------------------------------
__global__ void __launch_bounds__(256)
final_gemm(const unsigned short* __restrict__ topsw,  // [128mt][32kq][64][8]
           const unsigned short* __restrict__ wfcsw,  // [2000nt][32kq][64][8]
           const float* __restrict__ bfc,
           float* __restrict__ out) {
  int tid = threadIdx.x, wave = tid >> 6, lane = tid & 63;
  int mtb = blockIdx.y * 8;
  int ntb = blockIdx.x * 16 + wave * 4;
  f32x4 acc[8][4];
  #pragma unroll
  for (int i = 0; i < 8; ++i)
    #pragma unroll
    for (int n = 0; n < 4; ++n) acc[i][n] = (f32x4){0.f, 0.f, 0.f, 0.f};
  const unsigned short* abase = topsw + (((long long)mtb * 32) << 9) + (lane << 3);
  const unsigned short* bbase = wfcsw + (((long long)ntb * 32) << 9) + (lane << 3);
  for (int kq = 0; kq < 32; ++kq) {
    bf16x8 bf[4];
    #pragma unroll
    for (int n = 0; n < 4; ++n)
      bf[n] = *reinterpret_cast<const bf16x8*>(bbase + (((n * 32 + kq)) << 9));
    #pragma unroll
    for (int i = 0; i < 8; ++i) {
      bf16x8 af = *reinterpret_cast<const bf16x8*>(abase + (((i * 32 + kq)) << 9));
      #pragma unroll
      for (int n = 0; n < 4; ++n)
        acc[i][n] = __builtin_amdgcn_mfma_f32_16x16x32_bf16(af, bf[n], acc[i][n], 0, 0, 0);
    }
  }
  int i4 = (lane >> 4) << 2;
  int nl = lane & 15;
  #pragma unroll
  for (int i = 0; i < 8; ++i) {
    int mt = mtb + i;
    #pragma unroll
    for (int n = 0; n < 4; ++n) {
      int v = (ntb + n) * 16 + nl;
      float bv = bfc[v];
      #pragma unroll
      for (int reg = 0; reg < 4; ++reg) {
        int m = mt * 16 + i4 + reg;        // m = t*32 + b
        int b = m & 31, t = m >> 5;
        out[((long long)b * TT + t) * VV + v] = acc[i][n][reg] + bv;
      }
    }
  }
}

// ---------------------------------------------------------------------------
// In-place row softmax over V=32000 (one block per (b,t) row)
// ---------------------------------------------------------------------------
__global__ void __launch_bounds__(256)
softmax_k(float* __restrict__ out) {
  float* p = out + (long long)blockIdx.x * VV;
  int tid = threadIdx.x;
  __shared__ float red[24];
  float m = -1e30f;
  for (int i = tid; i < VV; i += 256) m = fmaxf(m, p[i]);
  #pragma unroll
  for (int o = 32; o > 0; o >>= 1) m = fmaxf(m, __shfl_down(m, o, 64));
  if ((tid & 63) == 0) red[tid >> 6] = m;
  __syncthreads();
  if (tid == 0) red[8] = fmaxf(fmaxf(red[0], red[1]), fmaxf(red[2], red[3]));
  __syncthreads();
  float mm = red[8];
  float s = 0.f;
  for (int i = tid; i < VV; i += 256) s += __expf(p[i] - mm);
  #pragma unroll
  for (int o = 32; o > 0; o >>= 1) s += __shfl_down(s, o, 64);
  if ((tid & 63) == 0) red[16 + (tid >> 6)] = s;
  __syncthreads();
  if (tid == 0) red[9] = 1.f / (red[16] + red[17] + red[18] + red[19]);
  __syncthreads();
  float inv = red[9];
  for (int i = tid; i < VV; i += 256) p[i] = __expf(p[i] - mm) * inv;
}

// ---------------------------------------------------------------------------
extern "C" void kernel_launch(void* const* d_in, const int* in_sizes, int n_in,
                              void* d_out, int out_size, void* d_ws, size_t ws_size,
                              hipStream_t stream) {
  const int*   tok    = (const int*)  d_in[0];
  const float* states = (const float*)d_in[1];
  const float* emb    = (const float*)d_in[2];
  const float* Wx     = (const float*)d_in[3];
  const float* Wh     = (const float*)d_in[4];
  const float* bias   = (const float*)d_in[5];
  const float* Wfc    = (const float*)d_in[6];
  const float* bfc    = (const float*)d_in[7];
  float* out = (float*)d_out;

  char* ws = (char*)d_ws;
  unsigned* ctr = (unsigned*)ws;
  size_t off = 256;
  unsigned short* Wsw   = (unsigned short*)(ws + off); off += (size_t)8 * 1024 * 4096 * 2;   // 67.1 MB
  unsigned short* Wfcsw = (unsigned short*)(ws + off); off += (size_t)VV * HH * 2;           // 65.5 MB
  unsigned short* xsw   = (unsigned short*)(ws + off); off += (size_t)TT * 32768 * 2;        // 4.2 MB
  unsigned short* topsw = (unsigned short*)(ws + off); off += (size_t)TT * 32768 * 2;        // 4.2 MB
  unsigned short* hsw   = (unsigned short*)(ws + off); off += (size_t)8 * 32768 * 2;         // 0.5 MB

  hipMemsetAsync(ctr, 0, 256, stream);

  // Wx -> even lmat slots, Wh -> odd lmat slots (gate-interleaved col tiles)
  swizzle_w<<<dim3(16, 64, 4), 256, 0, stream>>>(
      Wx, Wsw, HH, 4 * HH, 1, (long long)HH * 4 * HH, (long long)2 * HH * 4 * HH);
  swizzle_w<<<dim3(16, 64, 4), 256, 0, stream>>>(
      Wh, Wsw + (size_t)HH * 4 * HH, HH, 4 * HH, 1,
      (long long)HH * 4 * HH, (long long)2 * HH * 4 * HH);
  // Wfc plain 16-col tiles
  swizzle_w<<<dim3(16, 500, 1), 256, 0, stream>>>(Wfc, Wfcsw, HH, VV, 0, 0, 0);

  embed_swz<<<1024, 256, 0, stream>>>(tok, emb, xsw);
  init_h<<<64, 256, 0, stream>>>(states, hsw);

  lstm_kernel<<<256, 512, 0, stream>>>(Wsw, bias, xsw, hsw, states, topsw, ctr);

  final_gemm<<<dim3(125, 16), 256, 0, stream>>>(topsw, Wfcsw, bfc, out);
  softmax_k<<<BB * TT, 256, 0, stream>>>(out);
}

// Round 3
// 2039.860 us; speedup vs baseline: 2.8639x; 2.3446x over previous
//
#include <hip/hip_runtime.h>
#include <stdint.h>

// TrianDecoder: 4-layer LSTM (B=32, T=64, H=1024) + vocab projection (V=32000) + softmax.
// Round-2 result: register-resident weights cut FETCH 2.38GB -> 119MB but dur only
// 4747 -> 3759us. Kernel is now pure sync floor: 256 grid barriers x 14.7us
// (serialized same-line atomics + per-block agent-acquire L2 invalidates + input reload).
// This revision:
//   1) LAYER-DIAGONAL WAVEFRONT: anti-diagonal d = t + l, all 4 layers run concurrently
//      on different t. Grid barriers 256 -> 67. 64 blocks/layer, 16 h-cols/block;
//      per-wave weights still 128 VGPRs (one layer per block).
//   2) HIERARCHICAL BARRIER: 8 group counters (32 blocks each, own cacheline) -> 1
//      global counter -> 1 flag. ~40 serialized RMWs/step instead of 256.
//   3) bias in registers (was re-missed from global every step after invalidate).

#define NL 4
#define BB 32
#define TT 64
#define HH 1024
#define VV 32000

typedef __attribute__((ext_vector_type(8))) short bf16x8;
typedef __attribute__((ext_vector_type(4))) float f32x4;

__device__ __forceinline__ unsigned short f2bf(float f) {
  union { float f; unsigned u; } v; v.f = f;
  unsigned u = v.u;
  u = u + 0x7fffu + ((u >> 16) & 1u);   // RNE
  return (unsigned short)(u >> 16);
}

// ---------------------------------------------------------------------------
// Generic weight swizzler: src fp32 row-major (K x N), dst bf16 fragment layout
// [nt][kq][lane][8] for mfma_f32_16x16x32_bf16 A/B operands:
//   lane holds elem [row/col = tilebase + (lane&15)][k = kq*32 + (lane>>4)*8 + j]
// mode 0 (plain):  col(nt,i) = nt*16 + i                     (Wfc)
// mode 1 (lstm):   col(nt,i) = (i>>2)*1024 + nt*4 + (i&3)    (gate-interleaved tiles)
// ---------------------------------------------------------------------------
__global__ void __launch_bounds__(256)
swizzle_w(const float* __restrict__ src, unsigned short* __restrict__ dst,
          int K, int N, int mode, long long src_lstride, long long dst_lstride) {
  int l = blockIdx.z;
  src += (long long)l * src_lstride;
  dst += (long long)l * dst_lstride;
  int k0  = blockIdx.x * 64;
  int ntb = blockIdx.y;            // group of 4 n-tiles (64 cols)
  __shared__ float lds[64][65];
  int tid = threadIdx.x;
  for (int it = 0; it < 16; ++it) {
    int idx = tid + it * 256;      // 0..4095
    int kk = idx >> 6;
    int cl = idx & 63;
    int col;
    if (mode == 1) col = ((cl >> 4) << 10) + ntb * 16 + (cl & 15);
    else           col = ntb * 64 + cl;
    lds[kk][cl] = src[(long long)(k0 + kk) * N + col];
  }
  __syncthreads();
  int kqn = K >> 5;
  for (int p = 0; p < 2; ++p) {
    int o = tid + p * 256;         // 0..511
    int lane = o & 63;
    int kql  = (o >> 6) & 1;
    int ntl  = o >> 7;             // 0..3
    int i = lane & 15;
    int kloc = kql * 32 + ((lane >> 4) << 3);
    int clocal;
    if (mode == 1) clocal = ((i >> 2) << 4) + ntl * 4 + (i & 3);
    else           clocal = ntl * 16 + i;
    unsigned short o8[8] __attribute__((aligned(16)));
    #pragma unroll
    for (int j = 0; j < 8; ++j) o8[j] = f2bf(lds[kloc + j][clocal]);
    int nt = ntb * 4 + ntl;
    int kq = (k0 >> 5) + kql;
    long long doff = ((((long long)nt * kqn) + kq) << 9) + (lane << 3);
    *reinterpret_cast<uint4*>(dst + doff) = *reinterpret_cast<const uint4*>(o8);
  }
}

// ---------------------------------------------------------------------------
// Embedding gather -> bf16 swizzled activation x_sw[t] ([rt][kq][lane][8], 32768 elems/t)
// ---------------------------------------------------------------------------
__global__ void __launch_bounds__(256)
embed_swz(const int* __restrict__ tok, const float* __restrict__ emb,
          unsigned short* __restrict__ xsw) {
  int gid = blockIdx.x * 256 + threadIdx.x;   // 64t * 2rt * 32kq * 64lane = 262144
  int lane = gid & 63;
  int kq = (gid >> 6) & 31;
  int rt = (gid >> 11) & 1;
  int t  = gid >> 12;
  int r = rt * 16 + (lane & 15);
  int k = kq * 32 + (((lane >> 4) & 3) << 3);
  int token = tok[r * TT + t];                // batch_target_in[b=r][t]
  const float* s = emb + (long long)token * HH + k;
  unsigned short o8[8] __attribute__((aligned(16)));
  #pragma unroll
  for (int j = 0; j < 8; ++j) o8[j] = f2bf(s[j]);
  long long off = (long long)t * 32768 + (((rt * 32 + kq) * 64 + lane) << 3);
  *reinterpret_cast<uint4*>(xsw + off) = *reinterpret_cast<const uint4*>(o8);
}

// ---------------------------------------------------------------------------
// Init h (bf16 swizzled, parity slot 1) from states
// ---------------------------------------------------------------------------
__global__ void __launch_bounds__(256)
init_h(const float* __restrict__ states, unsigned short* __restrict__ hsw) {
  int gid = blockIdx.x * 256 + threadIdx.x;   // 4l * 2rt * 32kq * 64lane = 16384
  int lane = gid & 63;
  int kq = (gid >> 6) & 31;
  int rt = (gid >> 11) & 1;
  int l  = gid >> 12;
  int r = rt * 16 + (lane & 15);
  int k = kq * 32 + (((lane >> 4) & 3) << 3);
  const float* hs = states + (long long)(2 * l) * (BB * HH) + r * HH + k;
  unsigned short o8[8] __attribute__((aligned(16)));
  #pragma unroll
  for (int j = 0; j < 8; ++j) o8[j] = f2bf(hs[j]);
  long long off = (long long)(l * 2 + 1) * 32768 + (((rt * 32 + kq) * 64 + lane) << 3);
  *reinterpret_cast<uint4*>(hsw + off) = *reinterpret_cast<const uint4*>(o8);
}

// ---------------------------------------------------------------------------
// Persistent LSTM, layer-diagonal wavefront. 256 blocks x 512 threads, 1 block/CU.
// bid: layer = bid & 3, colgroup g = bid >> 2 (0..63). Block owns h-cols
// [g*16, g*16+16) of its layer -> 64 z-cols (x4 gates, gate-interleaved n-tiles
// nt = g*4 + ct). Wave w: mat = w>>2 (0:Wx path, 1:Wh path), kq-quarter = w&3.
// Weights: wreg[ct 4][s 8] = 128 VGPRs/wave, one layer only. Loaded once.
// Diagonal step d (0..66): layer processes t = d - layer if in range.
// ---------------------------------------------------------------------------
__global__ void __launch_bounds__(512, 2)
lstm_kernel(const unsigned short* __restrict__ Wsw,  // [l*2+mat][256nt][32kq][64][8]
            const float* __restrict__ bias,          // (4, 4096)
            const unsigned short* __restrict__ xsw,  // [64t][32768]
            unsigned short* hsw,                     // [l*2+parity][32768]
            const float* __restrict__ states,        // (8, 32, 1024) for c init
            unsigned short* topsw,                   // [64t][32768]
            unsigned* sync) {                        // [0]=flag [32]=glb [64+g*32]=grp
  const int tid  = threadIdx.x;
  const int wave = tid >> 6;
  const int lane = tid & 63;
  const int bid  = blockIdx.x;
  const int layer = bid & 3;
  const int g     = bid >> 2;             // col-group within layer, 0..63
  const int mat  = wave >> 2;             // 0: Wx*inp, 1: Wh*hprev
  const int kqb  = (wave & 3) << 3;       // kq range [kqb, kqb+8)

  __shared__ float zsh[8][64][34];        // [wave][c-local 64][r 32] (+pad)

  // ---- one-time weight preload: 32 fragments = 128 VGPRs/wave ----
  bf16x8 wreg[4][8];
  #pragma unroll
  for (int ct = 0; ct < 4; ++ct) {
    const unsigned short* wb =
        Wsw + ((((long long)(layer * 2 + mat) * 256 + (g * 4 + ct)) * 32 + kqb) << 9)
            + (lane << 3);
    #pragma unroll
    for (int s = 0; s < 8; ++s)
      wreg[ct][s] = *reinterpret_cast<const bf16x8*>(wb + (s << 9));
  }

  // ---- per-thread gate state: thread = (r, jj), jcol = g*16 + jj ----
  const int r    = tid & 31;
  const int jj   = tid >> 5;              // 0..15
  const int jcol = g * 16 + jj;
  float cR = states[(long long)(2 * layer + 1) * (BB * HH) + r * HH + jcol];
  float bia[4];
  #pragma unroll
  for (int q = 0; q < 4; ++q) bia[q] = bias[(layer << 12) + (q << 10) + jcol];

  const int i4 = (lane >> 4) << 2;
  const int rl = lane & 15;
  // h store offset (swizzled fragment layout)
  const int hrt = r >> 4, hkq = jcol >> 5;
  const int hln = (r & 15) | (((jcol >> 3) & 3) << 4);
  const int hoff = (((hrt << 5) | hkq) << 9) | (hln << 3) | (jcol & 7);
  const int zb = ((jj >> 2) << 4) + (jj & 3);   // zsh row base = ct*16 + (i&3)

  unsigned* grp = sync + 64 + ((bid >> 5) << 5);

  const int ND = TT + NL - 1;             // 67 diagonal steps
  for (int d = 0; d < ND; ++d) {
    const int t = d - layer;
    if (t >= 0 && t < TT) {
      const unsigned short* ibase;
      if (mat == 0)
        ibase = (layer == 0) ? (xsw + (long long)t * 32768)
                             : (hsw + (long long)((layer - 1) * 2 + (t & 1)) * 32768);
      else
        ibase = hsw + (long long)(layer * 2 + ((t + 1) & 1)) * 32768;
      ibase += (kqb << 9) + (lane << 3);

      f32x4 acc[4][2];
      #pragma unroll
      for (int ct = 0; ct < 4; ++ct) {
        acc[ct][0] = (f32x4){0.f, 0.f, 0.f, 0.f};
        acc[ct][1] = (f32x4){0.f, 0.f, 0.f, 0.f};
      }
      #pragma unroll
      for (int s = 0; s < 8; ++s) {
        bf16x8 b0 = *reinterpret_cast<const bf16x8*>(ibase + (s << 9));
        bf16x8 b1 = *reinterpret_cast<const bf16x8*>(ibase + 16384 + (s << 9));
        #pragma unroll
        for (int ct = 0; ct < 4; ++ct) {
          acc[ct][0] = __builtin_amdgcn_mfma_f32_16x16x32_bf16(wreg[ct][s], b0, acc[ct][0], 0, 0, 0);
          acc[ct][1] = __builtin_amdgcn_mfma_f32_16x16x32_bf16(wreg[ct][s], b1, acc[ct][1], 0, 0, 0);
        }
      }
      #pragma unroll
      for (int ct = 0; ct < 4; ++ct) {
        #pragma unroll
        for (int reg = 0; reg < 4; ++reg) {
          zsh[wave][ct * 16 + i4 + reg][rl]      = acc[ct][0][reg];
          zsh[wave][ct * 16 + i4 + reg][16 + rl] = acc[ct][1][reg];
        }
      }
      __syncthreads();
      // gates: all 512 threads, one (r, jcol) each
      {
        float zg[4];
        #pragma unroll
        for (int q = 0; q < 4; ++q) {
          int zr = zb + (q << 2);
          float z = 0.f;
          #pragma unroll
          for (int w = 0; w < 8; ++w) z += zsh[w][zr][r];
          zg[q] = z + bia[q];
        }
        float si = 1.f / (1.f + __expf(-zg[0]));
        float sf = 1.f / (1.f + __expf(-zg[1]));
        float so = 1.f / (1.f + __expf(-zg[3]));
        float e2 = __expf(-2.f * fabsf(zg[2]));
        float tg = (1.f - e2) / (1.f + e2);
        tg = zg[2] < 0.f ? -tg : tg;
        float cnew = sf * cR + si * tg;
        cR = cnew;
        float e2c = __expf(-2.f * fabsf(cnew));
        float th = (1.f - e2c) / (1.f + e2c);
        th = cnew < 0.f ? -th : th;
        unsigned short hb = f2bf(so * th);
        hsw[(long long)(layer * 2 + (t & 1)) * 32768 + hoff] = hb;
        if (layer == 3) topsw[(long long)t * 32768 + hoff] = hb;
      }
    }
    if (d == ND - 1) break;
    // ---- hierarchical grid barrier ----
    __syncthreads();
    if (tid == 0) {
      unsigned step = (unsigned)(d + 1);
      unsigned old = __hip_atomic_fetch_add(grp, 1u, __ATOMIC_RELEASE,
                                            __HIP_MEMORY_SCOPE_AGENT);
      if (old == 32u * step - 1u) {
        (void)__hip_atomic_load(grp, __ATOMIC_ACQUIRE, __HIP_MEMORY_SCOPE_AGENT);
        unsigned o2 = __hip_atomic_fetch_add(sync + 32, 1u, __ATOMIC_RELEASE,
                                             __HIP_MEMORY_SCOPE_AGENT);
        if (o2 == 8u * step - 1u) {
          (void)__hip_atomic_load(sync + 32, __ATOMIC_ACQUIRE, __HIP_MEMORY_SCOPE_AGENT);
          __hip_atomic_store(sync, step, __ATOMIC_RELEASE, __HIP_MEMORY_SCOPE_AGENT);
        }
      }
      while (__hip_atomic_load(sync, __ATOMIC_RELAXED, __HIP_MEMORY_SCOPE_AGENT) < step)
        __builtin_amdgcn_s_sleep(2);
      (void)__hip_atomic_load(sync, __ATOMIC_ACQUIRE, __HIP_MEMORY_SCOPE_AGENT);
    }
    __syncthreads();
  }
}

// ---------------------------------------------------------------------------
// Projection: logits(2048 x 32000) = tops(2048x1024) @ Wfc(1024x32000) + bfc
// ---------------------------------------------------------------------------
__global__ void __launch_bounds__(256)
final_gemm(const unsigned short* __restrict__ topsw,  // [128mt][32kq][64][8]
           const unsigned short* __restrict__ wfcsw,  // [2000nt][32kq][64][8]
           const float* __restrict__ bfc,
           float* __restrict__ out) {
  int tid = threadIdx.x, wave = tid >> 6, lane = tid & 63;
  int mtb = blockIdx.y * 8;
  int ntb = blockIdx.x * 16 + wave * 4;
  f32x4 acc[8][4];
  #pragma unroll
  for (int i = 0; i < 8; ++i)
    #pragma unroll
    for (int n = 0; n < 4; ++n) acc[i][n] = (f32x4){0.f, 0.f, 0.f, 0.f};
  const unsigned short* abase = topsw + (((long long)mtb * 32) << 9) + (lane << 3);
  const unsigned short* bbase = wfcsw + (((long long)ntb * 32) << 9) + (lane << 3);
  for (int kq = 0; kq < 32; ++kq) {
    bf16x8 bf[4];
    #pragma unroll
    for (int n = 0; n < 4; ++n)
      bf[n] = *reinterpret_cast<const bf16x8*>(bbase + (((n * 32 + kq)) << 9));
    #pragma unroll
    for (int i = 0; i < 8; ++i) {
      bf16x8 af = *reinterpret_cast<const bf16x8*>(abase + (((i * 32 + kq)) << 9));
      #pragma unroll
      for (int n = 0; n < 4; ++n)
        acc[i][n] = __builtin_amdgcn_mfma_f32_16x16x32_bf16(af, bf[n], acc[i][n], 0, 0, 0);
    }
  }
  int i4 = (lane >> 4) << 2;
  int nl = lane & 15;
  #pragma unroll
  for (int i = 0; i < 8; ++i) {
    int mt = mtb + i;
    #pragma unroll
    for (int n = 0; n < 4; ++n) {
      int v = (ntb + n) * 16 + nl;
      float bv = bfc[v];
      #pragma unroll
      for (int reg = 0; reg < 4; ++reg) {
        int m = mt * 16 + i4 + reg;        // m = t*32 + b
        int b = m & 31, t = m >> 5;
        out[((long long)b * TT + t) * VV + v] = acc[i][n][reg] + bv;
      }
    }
  }
}

// ---------------------------------------------------------------------------
// In-place row softmax over V=32000 (one block per (b,t) row)
// ---------------------------------------------------------------------------
__global__ void __launch_bounds__(256)
softmax_k(float* __restrict__ out) {
  float* p = out + (long long)blockIdx.x * VV;
  int tid = threadIdx.x;
  __shared__ float red[24];
  float m = -1e30f;
  for (int i = tid; i < VV; i += 256) m = fmaxf(m, p[i]);
  #pragma unroll
  for (int o = 32; o > 0; o >>= 1) m = fmaxf(m, __shfl_down(m, o, 64));
  if ((tid & 63) == 0) red[tid >> 6] = m;
  __syncthreads();
  if (tid == 0) red[8] = fmaxf(fmaxf(red[0], red[1]), fmaxf(red[2], red[3]));
  __syncthreads();
  float mm = red[8];
  float s = 0.f;
  for (int i = tid; i < VV; i += 256) s += __expf(p[i] - mm);
  #pragma unroll
  for (int o = 32; o > 0; o >>= 1) s += __shfl_down(s, o, 64);
  if ((tid & 63) == 0) red[16 + (tid >> 6)] = s;
  __syncthreads();
  if (tid == 0) red[9] = 1.f / (red[16] + red[17] + red[18] + red[19]);
  __syncthreads();
  float inv = red[9];
  for (int i = tid; i < VV; i += 256) p[i] = __expf(p[i] - mm) * inv;
}

// ---------------------------------------------------------------------------
extern "C" void kernel_launch(void* const* d_in, const int* in_sizes, int n_in,
                              void* d_out, int out_size, void* d_ws, size_t ws_size,
                              hipStream_t stream) {
  const int*   tok    = (const int*)  d_in[0];
  const float* states = (const float*)d_in[1];
  const float* emb    = (const float*)d_in[2];
  const float* Wx     = (const float*)d_in[3];
  const float* Wh     = (const float*)d_in[4];
  const float* bias   = (const float*)d_in[5];
  const float* Wfc    = (const float*)d_in[6];
  const float* bfc    = (const float*)d_in[7];
  float* out = (float*)d_out;

  char* ws = (char*)d_ws;
  unsigned* sync = (unsigned*)ws;
  size_t off = 2048;
  unsigned short* Wsw   = (unsigned short*)(ws + off); off += (size_t)8 * 1024 * 4096 * 2;   // 67.1 MB
  unsigned short* Wfcsw = (unsigned short*)(ws + off); off += (size_t)VV * HH * 2;           // 65.5 MB
  unsigned short* xsw   = (unsigned short*)(ws + off); off += (size_t)TT * 32768 * 2;        // 4.2 MB
  unsigned short* topsw = (unsigned short*)(ws + off); off += (size_t)TT * 32768 * 2;        // 4.2 MB
  unsigned short* hsw   = (unsigned short*)(ws + off); off += (size_t)8 * 32768 * 2;         // 0.5 MB

  hipMemsetAsync(sync, 0, 2048, stream);

  // Wx -> even lmat slots, Wh -> odd lmat slots (gate-interleaved col tiles)
  swizzle_w<<<dim3(16, 64, 4), 256, 0, stream>>>(
      Wx, Wsw, HH, 4 * HH, 1, (long long)HH * 4 * HH, (long long)2 * HH * 4 * HH);
  swizzle_w<<<dim3(16, 64, 4), 256, 0, stream>>>(
      Wh, Wsw + (size_t)HH * 4 * HH, HH, 4 * HH, 1,
      (long long)HH * 4 * HH, (long long)2 * HH * 4 * HH);
  // Wfc plain 16-col tiles
  swizzle_w<<<dim3(16, 500, 1), 256, 0, stream>>>(Wfc, Wfcsw, HH, VV, 0, 0, 0);

  embed_swz<<<1024, 256, 0, stream>>>(tok, emb, xsw);
  init_h<<<64, 256, 0, stream>>>(states, hsw);

  lstm_kernel<<<256, 512, 0, stream>>>(Wsw, bias, xsw, hsw, states, topsw, sync);

  final_gemm<<<dim3(125, 16), 256, 0, stream>>>(topsw, Wfcsw, bfc, out);
  softmax_k<<<BB * TT, 256, 0, stream>>>(out);
}

// Round 4
// 1693.469 us; speedup vs baseline: 3.4497x; 1.2045x over previous
//
#include <hip/hip_runtime.h>
#include <stdint.h>

// TrianDecoder: 4-layer LSTM (B=32, T=64, H=1024) + vocab projection (V=32000) + softmax.
// Round-3 finding: per-step cost 14.2us identical to round-2's 14.7 despite 8x fewer
// serialized RMWs -> the barrier atomics are NOT the cost. The invariants were the
// agent-acquire L1/L2 invalidate + release writeback + post-invalidate reload + global
// straggler fan-in. This revision removes them structurally:
//   1) FULL h HISTORY hsw[l][t] (write-once addresses): consumers can use PLAIN cached
//      loads with no acquire/invalidate ever (no address is ever stale anywhere);
//      producers push h via bypass (relaxed-agent atomic) dword stores.
//   2) DATAFLOW SYNC: per-(layer,t) counters; 64 producers release-add; each consumer
//      polls only its two dependencies. No grid barrier; layers pipeline.
//   3) h packed to u32 via shfl_xor(32) for the atomic stores.
//   4) softmax: float4 + online max/sum (4 -> 3 passes over 262 MB).

#define NL 4
#define BB 32
#define TT 64
#define HH 1024
#define VV 32000

typedef __attribute__((ext_vector_type(8))) short bf16x8;
typedef __attribute__((ext_vector_type(4))) float f32x4;

__device__ __forceinline__ unsigned short f2bf(float f) {
  union { float f; unsigned u; } v; v.f = f;
  unsigned u = v.u;
  u = u + 0x7fffu + ((u >> 16) & 1u);   // RNE
  return (unsigned short)(u >> 16);
}

// ---------------------------------------------------------------------------
// Generic weight swizzler: src fp32 row-major (K x N), dst bf16 fragment layout
// [nt][kq][lane][8] for mfma_f32_16x16x32_bf16 A/B operands:
//   lane holds elem [row/col = tilebase + (lane&15)][k = kq*32 + (lane>>4)*8 + j]
// mode 0 (plain):  col(nt,i) = nt*16 + i                     (Wfc)
// mode 1 (lstm):   col(nt,i) = (i>>2)*1024 + nt*4 + (i&3)    (gate-interleaved tiles)
// ---------------------------------------------------------------------------
__global__ void __launch_bounds__(256)
swizzle_w(const float* __restrict__ src, unsigned short* __restrict__ dst,
          int K, int N, int mode, long long src_lstride, long long dst_lstride) {
  int l = blockIdx.z;
  src += (long long)l * src_lstride;
  dst += (long long)l * dst_lstride;
  int k0  = blockIdx.x * 64;
  int ntb = blockIdx.y;            // group of 4 n-tiles (64 cols)
  __shared__ float lds[64][65];
  int tid = threadIdx.x;
  for (int it = 0; it < 16; ++it) {
    int idx = tid + it * 256;      // 0..4095
    int kk = idx >> 6;
    int cl = idx & 63;
    int col;
    if (mode == 1) col = ((cl >> 4) << 10) + ntb * 16 + (cl & 15);
    else           col = ntb * 64 + cl;
    lds[kk][cl] = src[(long long)(k0 + kk) * N + col];
  }
  __syncthreads();
  int kqn = K >> 5;
  for (int p = 0; p < 2; ++p) {
    int o = tid + p * 256;         // 0..511
    int lane = o & 63;
    int kql  = (o >> 6) & 1;
    int ntl  = o >> 7;             // 0..3
    int i = lane & 15;
    int kloc = kql * 32 + ((lane >> 4) << 3);
    int clocal;
    if (mode == 1) clocal = ((i >> 2) << 4) + ntl * 4 + (i & 3);
    else           clocal = ntl * 16 + i;
    unsigned short o8[8] __attribute__((aligned(16)));
    #pragma unroll
    for (int j = 0; j < 8; ++j) o8[j] = f2bf(lds[kloc + j][clocal]);
    int nt = ntb * 4 + ntl;
    int kq = (k0 >> 5) + kql;
    long long doff = ((((long long)nt * kqn) + kq) << 9) + (lane << 3);
    *reinterpret_cast<uint4*>(dst + doff) = *reinterpret_cast<const uint4*>(o8);
  }
}

// ---------------------------------------------------------------------------
// Embedding gather -> bf16 swizzled activation x_sw[t] ([rt][kq][lane][8], 32768 elems/t)
// ---------------------------------------------------------------------------
__global__ void __launch_bounds__(256)
embed_swz(const int* __restrict__ tok, const float* __restrict__ emb,
          unsigned short* __restrict__ xsw) {
  int gid = blockIdx.x * 256 + threadIdx.x;   // 64t * 2rt * 32kq * 64lane = 262144
  int lane = gid & 63;
  int kq = (gid >> 6) & 31;
  int rt = (gid >> 11) & 1;
  int t  = gid >> 12;
  int r = rt * 16 + (lane & 15);
  int k = kq * 32 + (((lane >> 4) & 3) << 3);
  int token = tok[r * TT + t];                // batch_target_in[b=r][t]
  const float* s = emb + (long long)token * HH + k;
  unsigned short o8[8] __attribute__((aligned(16)));
  #pragma unroll
  for (int j = 0; j < 8; ++j) o8[j] = f2bf(s[j]);
  long long off = (long long)t * 32768 + (((rt * 32 + kq) * 64 + lane) << 3);
  *reinterpret_cast<uint4*>(xsw + off) = *reinterpret_cast<const uint4*>(o8);
}

// ---------------------------------------------------------------------------
// Init h history slot 0 (bf16 swizzled) from states
// ---------------------------------------------------------------------------
__global__ void __launch_bounds__(256)
init_h(const float* __restrict__ states, unsigned short* __restrict__ hsw) {
  int gid = blockIdx.x * 256 + threadIdx.x;   // 4l * 2rt * 32kq * 64lane = 16384
  int lane = gid & 63;
  int kq = (gid >> 6) & 31;
  int rt = (gid >> 11) & 1;
  int l  = gid >> 12;
  int r = rt * 16 + (lane & 15);
  int k = kq * 32 + (((lane >> 4) & 3) << 3);
  const float* hs = states + (long long)(2 * l) * (BB * HH) + r * HH + k;
  unsigned short o8[8] __attribute__((aligned(16)));
  #pragma unroll
  for (int j = 0; j < 8; ++j) o8[j] = f2bf(hs[j]);
  long long off = (long long)(l * (TT + 1)) * 32768 + (((rt * 32 + kq) * 64 + lane) << 3);
  *reinterpret_cast<uint4*>(hsw + off) = *reinterpret_cast<const uint4*>(o8);
}

// ---------------------------------------------------------------------------
// Persistent LSTM, dataflow-synchronized. 256 blocks x 512 threads, 1 block/CU.
// bid: layer = bid & 3, colgroup g = bid >> 2 (0..63). Block owns h-cols
// [g*16, g*16+16) of its layer -> 64 z-cols. Wave w: mat = w>>2, kq-quarter = w&3.
// Weights: wreg[ct 4][s 8] = 128 VGPRs/wave, loaded once.
// h history: hsw[l][t+1] slot written once; slot 0 = initial h. Plain cached input
// loads (no address ever stale); bypass atomic u32 stores push h to L3.
// cnt[l][t] (64B-strided): producers release-add; consumers poll their 2 deps.
// ---------------------------------------------------------------------------
__global__ void __launch_bounds__(512, 2)
lstm_kernel(const unsigned short* __restrict__ Wsw,  // [l*2+mat][256nt][32kq][64][8]
            const float* __restrict__ bias,          // (4, 4096)
            const unsigned short* __restrict__ xsw,  // [64t][32768]
            unsigned short* hsw,                     // [l][65 slots][32768]
            const float* __restrict__ states,        // (8, 32, 1024) for c init
            unsigned short* topsw,                   // [64t][32768]
            unsigned* sync) {                        // cnt[l][t] at [(l*64+t)*16]
  const int tid  = threadIdx.x;
  const int wave = tid >> 6;
  const int lane = tid & 63;
  const int bid  = blockIdx.x;
  const int layer = bid & 3;
  const int g     = bid >> 2;             // col-group within layer, 0..63
  const int mat  = wave >> 2;             // 0: Wx*inp, 1: Wh*hprev
  const int kqb  = (wave & 3) << 3;       // kq range [kqb, kqb+8)

  __shared__ float zsh[8][64][34];        // [wave][c-local 64][r 32] (+pad)

  // ---- one-time weight preload: 32 fragments = 128 VGPRs/wave ----
  bf16x8 wreg[4][8];
  #pragma unroll
  for (int ct = 0; ct < 4; ++ct) {
    const unsigned short* wb =
        Wsw + ((((long long)(layer * 2 + mat) * 256 + (g * 4 + ct)) * 32 + kqb) << 9)
            + (lane << 3);
    #pragma unroll
    for (int s = 0; s < 8; ++s)
      wreg[ct][s] = *reinterpret_cast<const bf16x8*>(wb + (s << 9));
  }

  // ---- per-thread gate state: thread = (r, jj), jcol = g*16 + jj ----
  const int r    = tid & 31;
  const int jj   = tid >> 5;              // 0..15
  const int jcol = g * 16 + jj;
  float cR = states[(long long)(2 * layer + 1) * (BB * HH) + r * HH + jcol];
  float bia[4];
  #pragma unroll
  for (int q = 0; q < 4; ++q) bia[q] = bias[(layer << 12) + (q << 10) + jcol];

  const int i4 = (lane >> 4) << 2;
  const int rl = lane & 15;
  const int hrt = r >> 4, hkq = jcol >> 5;
  const int hln = (r & 15) | (((jcol >> 3) & 3) << 4);
  const int hoff = (((hrt << 5) | hkq) << 9) | (hln << 3) | (jcol & 7);
  const int zb = ((jj >> 2) << 4) + (jj & 3);   // zsh row base = ct*16 + (i&3)

  for (int t = 0; t < TT; ++t) {
    // ---- dataflow wait: two pollers in different waves, then join ----
    if (t > 0 && tid == 0) {
      const unsigned* c0 = sync + ((layer * TT + (t - 1)) << 4);
      while (__hip_atomic_load(c0, __ATOMIC_RELAXED, __HIP_MEMORY_SCOPE_AGENT) < 64u)
        __builtin_amdgcn_s_sleep(1);
    }
    if (layer > 0 && tid == 64) {
      const unsigned* c1 = sync + (((layer - 1) * TT + t) << 4);
      while (__hip_atomic_load(c1, __ATOMIC_RELAXED, __HIP_MEMORY_SCOPE_AGENT) < 64u)
        __builtin_amdgcn_s_sleep(1);
    }
    __syncthreads();

    // ---- inputs: plain cached fragment loads (addresses are write-once-fresh) ----
    const unsigned short* ibase;
    if (mat == 0)
      ibase = (layer == 0) ? (xsw + (long long)t * 32768)
                           : (hsw + (long long)((layer - 1) * (TT + 1) + t + 1) * 32768);
    else
      ibase = hsw + (long long)(layer * (TT + 1) + t) * 32768;
    ibase += (kqb << 9) + (lane << 3);

    f32x4 acc[4][2];
    #pragma unroll
    for (int ct = 0; ct < 4; ++ct) {
      acc[ct][0] = (f32x4){0.f, 0.f, 0.f, 0.f};
      acc[ct][1] = (f32x4){0.f, 0.f, 0.f, 0.f};
    }
    #pragma unroll
    for (int s = 0; s < 8; ++s) {
      bf16x8 b0 = *reinterpret_cast<const bf16x8*>(ibase + (s << 9));
      bf16x8 b1 = *reinterpret_cast<const bf16x8*>(ibase + 16384 + (s << 9));
      #pragma unroll
      for (int ct = 0; ct < 4; ++ct) {
        acc[ct][0] = __builtin_amdgcn_mfma_f32_16x16x32_bf16(wreg[ct][s], b0, acc[ct][0], 0, 0, 0);
        acc[ct][1] = __builtin_amdgcn_mfma_f32_16x16x32_bf16(wreg[ct][s], b1, acc[ct][1], 0, 0, 0);
      }
    }
    #pragma unroll
    for (int ct = 0; ct < 4; ++ct) {
      #pragma unroll
      for (int reg = 0; reg < 4; ++reg) {
        zsh[wave][ct * 16 + i4 + reg][rl]      = acc[ct][0][reg];
        zsh[wave][ct * 16 + i4 + reg][16 + rl] = acc[ct][1][reg];
      }
    }
    __syncthreads();

    // ---- gates: all 512 threads, one (r, jcol) each ----
    float zg[4];
    #pragma unroll
    for (int q = 0; q < 4; ++q) {
      int zr = zb + (q << 2);
      float z = 0.f;
      #pragma unroll
      for (int w = 0; w < 8; ++w) z += zsh[w][zr][r];
      zg[q] = z + bia[q];
    }
    float si = 1.f / (1.f + __expf(-zg[0]));
    float sf = 1.f / (1.f + __expf(-zg[1]));
    float so = 1.f / (1.f + __expf(-zg[3]));
    float e2 = __expf(-2.f * fabsf(zg[2]));
    float tg = (1.f - e2) / (1.f + e2);
    tg = zg[2] < 0.f ? -tg : tg;
    float cnew = sf * cR + si * tg;
    cR = cnew;
    float e2c = __expf(-2.f * fabsf(cnew));
    float th = (1.f - e2c) / (1.f + e2c);
    th = cnew < 0.f ? -th : th;
    unsigned short hb = f2bf(so * th);

    // ---- pack pairs (jj, jj^1) via shfl_xor(32) -> one u32 bypass store ----
    unsigned hv = (unsigned)hb;
    unsigned pv = (unsigned)__shfl_xor((int)hv, 32, 64);
    if ((tid & 32) == 0) {                 // even jj: own = low short
      unsigned u = hv | (pv << 16);
      unsigned* hdst = (unsigned*)(hsw + (long long)(layer * (TT + 1) + t + 1) * 32768);
      __hip_atomic_store(hdst + (hoff >> 1), u, __ATOMIC_RELAXED,
                         __HIP_MEMORY_SCOPE_AGENT);
      if (layer == 3)
        ((unsigned*)(topsw + (long long)t * 32768))[hoff >> 1] = u;
    }

    // ---- drain stores block-wide, then signal h[layer][t] ready ----
    __syncthreads();
    if (tid == 0)
      __hip_atomic_fetch_add(sync + ((layer * TT + t) << 4), 1u,
                             __ATOMIC_RELEASE, __HIP_MEMORY_SCOPE_AGENT);
  }
}

// ---------------------------------------------------------------------------
// Projection: logits(2048 x 32000) = tops(2048x1024) @ Wfc(1024x32000) + bfc
// ---------------------------------------------------------------------------
__global__ void __launch_bounds__(256)
final_gemm(const unsigned short* __restrict__ topsw,  // [128mt][32kq][64][8]
           const unsigned short* __restrict__ wfcsw,  // [2000nt][32kq][64][8]
           const float* __restrict__ bfc,
           float* __restrict__ out) {
  int tid = threadIdx.x, wave = tid >> 6, lane = tid & 63;
  int mtb = blockIdx.y * 8;
  int ntb = blockIdx.x * 16 + wave * 4;
  f32x4 acc[8][4];
  #pragma unroll
  for (int i = 0; i < 8; ++i)
    #pragma unroll
    for (int n = 0; n < 4; ++n) acc[i][n] = (f32x4){0.f, 0.f, 0.f, 0.f};
  const unsigned short* abase = topsw + (((long long)mtb * 32) << 9) + (lane << 3);
  const unsigned short* bbase = wfcsw + (((long long)ntb * 32) << 9) + (lane << 3);
  for (int kq = 0; kq < 32; ++kq) {
    bf16x8 bf[4];
    #pragma unroll
    for (int n = 0; n < 4; ++n)
      bf[n] = *reinterpret_cast<const bf16x8*>(bbase + (((n * 32 + kq)) << 9));
    #pragma unroll
    for (int i = 0; i < 8; ++i) {
      bf16x8 af = *reinterpret_cast<const bf16x8*>(abase + (((i * 32 + kq)) << 9));
      #pragma unroll
      for (int n = 0; n < 4; ++n)
        acc[i][n] = __builtin_amdgcn_mfma_f32_16x16x32_bf16(af, bf[n], acc[i][n], 0, 0, 0);
    }
  }
  int i4 = (lane >> 4) << 2;
  int nl = lane & 15;
  #pragma unroll
  for (int i = 0; i < 8; ++i) {
    int mt = mtb + i;
    #pragma unroll
    for (int n = 0; n < 4; ++n) {
      int v = (ntb + n) * 16 + nl;
      float bv = bfc[v];
      #pragma unroll
      for (int reg = 0; reg < 4; ++reg) {
        int m = mt * 16 + i4 + reg;        // m = t*32 + b
        int b = m & 31, t = m >> 5;
        out[((long long)b * TT + t) * VV + v] = acc[i][n][reg] + bv;
      }
    }
  }
}

// ---------------------------------------------------------------------------
// In-place row softmax over V=32000 (one block per (b,t) row)
// float4 + online max/sum: 2 read passes + 1 write pass
// ---------------------------------------------------------------------------
__global__ void __launch_bounds__(256)
softmax_k(float* __restrict__ out) {
  float4* p4 = reinterpret_cast<float4*>(out + (long long)blockIdx.x * VV);
  int tid = threadIdx.x;
  __shared__ float redm[4], reds[4], fin[2];
  float m = -1e30f, s = 0.f;
  for (int i = tid; i < VV / 4; i += 256) {
    float4 v = p4[i];
    float lm = fmaxf(fmaxf(v.x, v.y), fmaxf(v.z, v.w));
    if (lm > m) { s *= __expf(m - lm); m = lm; }
    s += __expf(v.x - m) + __expf(v.y - m) + __expf(v.z - m) + __expf(v.w - m);
  }
  #pragma unroll
  for (int o = 32; o > 0; o >>= 1) {
    float om = __shfl_down(m, o, 64);
    float os = __shfl_down(s, o, 64);
    float nm = fmaxf(m, om);
    s = s * __expf(m - nm) + os * __expf(om - nm);
    m = nm;
  }
  if ((tid & 63) == 0) { redm[tid >> 6] = m; reds[tid >> 6] = s; }
  __syncthreads();
  if (tid == 0) {
    float M = redm[0], S = reds[0];
    #pragma unroll
    for (int w = 1; w < 4; ++w) {
      float nm = fmaxf(M, redm[w]);
      S = S * __expf(M - nm) + reds[w] * __expf(redm[w] - nm);
      M = nm;
    }
    fin[0] = M; fin[1] = 1.f / S;
  }
  __syncthreads();
  float M = fin[0], inv = fin[1];
  for (int i = tid; i < VV / 4; i += 256) {
    float4 v = p4[i];
    v.x = __expf(v.x - M) * inv;
    v.y = __expf(v.y - M) * inv;
    v.z = __expf(v.z - M) * inv;
    v.w = __expf(v.w - M) * inv;
    p4[i] = v;
  }
}

// ---------------------------------------------------------------------------
extern "C" void kernel_launch(void* const* d_in, const int* in_sizes, int n_in,
                              void* d_out, int out_size, void* d_ws, size_t ws_size,
                              hipStream_t stream) {
  const int*   tok    = (const int*)  d_in[0];
  const float* states = (const float*)d_in[1];
  const float* emb    = (const float*)d_in[2];
  const float* Wx     = (const float*)d_in[3];
  const float* Wh     = (const float*)d_in[4];
  const float* bias   = (const float*)d_in[5];
  const float* Wfc    = (const float*)d_in[6];
  const float* bfc    = (const float*)d_in[7];
  float* out = (float*)d_out;

  char* ws = (char*)d_ws;
  unsigned* sync = (unsigned*)ws;
  size_t off = 32768;
  unsigned short* Wsw   = (unsigned short*)(ws + off); off += (size_t)8 * 1024 * 4096 * 2;       // 67.1 MB
  unsigned short* Wfcsw = (unsigned short*)(ws + off); off += (size_t)VV * HH * 2;               // 65.5 MB
  unsigned short* xsw   = (unsigned short*)(ws + off); off += (size_t)TT * 32768 * 2;            // 4.2 MB
  unsigned short* topsw = (unsigned short*)(ws + off); off += (size_t)TT * 32768 * 2;            // 4.2 MB
  unsigned short* hsw   = (unsigned short*)(ws + off); off += (size_t)NL * (TT + 1) * 32768 * 2; // 17.0 MB

  hipMemsetAsync(sync, 0, 32768, stream);

  // Wx -> even lmat slots, Wh -> odd lmat slots (gate-interleaved col tiles)
  swizzle_w<<<dim3(16, 64, 4), 256, 0, stream>>>(
      Wx, Wsw, HH, 4 * HH, 1, (long long)HH * 4 * HH, (long long)2 * HH * 4 * HH);
  swizzle_w<<<dim3(16, 64, 4), 256, 0, stream>>>(
      Wh, Wsw + (size_t)HH * 4 * HH, HH, 4 * HH, 1,
      (long long)HH * 4 * HH, (long long)2 * HH * 4 * HH);
  // Wfc plain 16-col tiles
  swizzle_w<<<dim3(16, 500, 1), 256, 0, stream>>>(Wfc, Wfcsw, HH, VV, 0, 0, 0);

  embed_swz<<<1024, 256, 0, stream>>>(tok, emb, xsw);
  init_h<<<64, 256, 0, stream>>>(states, hsw);

  lstm_kernel<<<256, 512, 0, stream>>>(Wsw, bias, xsw, hsw, states, topsw, sync);

  final_gemm<<<dim3(125, 16), 256, 0, stream>>>(topsw, Wfcsw, bfc, out);
  softmax_k<<<BB * TT, 256, 0, stream>>>(out);
}